// Round 11
// baseline (332.958 us; speedup 1.0000x reference)
//
#include <hip/hip_runtime.h>

#define Bn  32
#define IDF 1024
#define CDF 1024
#define Qn  2304
#define Sn  256

typedef _Float16 f16;
typedef _Float16 f16x2 __attribute__((ext_vector_type(2)));
typedef _Float16 f16x4 __attribute__((ext_vector_type(4)));
typedef _Float16 f16x8 __attribute__((ext_vector_type(8)));
typedef float    f32x4 __attribute__((ext_vector_type(4)));

// async global->LDS, 16B per lane; dest = wave-uniform base + lane*16
__device__ __forceinline__ void gll16(const void* g, void* l) {
    __builtin_amdgcn_global_load_lds((const __attribute__((address_space(1))) void*)g,
                                     (__attribute__((address_space(3))) void*)l, 16, 0, 0);
}

// split fp32 into fp16 hi + fp16 lo (x ~= hi + lo, error ~2^-23*|x|)
__device__ __forceinline__ void fsplit(float x, f16& hi, f16& lo) {
    hi = (f16)x;
    lo = (f16)(x - (float)hi);
}

// ---------------------------------------------------------------------------
// K0: split W into fp16 hi/lo (runs once, ~4 MB traffic)
// ---------------------------------------------------------------------------
__global__ __launch_bounds__(256) void k_wsplit(const float* __restrict__ W,
                                                f16* __restrict__ Wh, f16* __restrict__ Wl) {
    const int idx = (blockIdx.x * 256 + threadIdx.x) * 4;
    const float4 v = *reinterpret_cast<const float4*>(&W[idx]);
    f16x4 h4, l4;
    f16 h, l;
    fsplit(v.x, h, l); h4[0] = h; l4[0] = l;
    fsplit(v.y, h, l); h4[1] = h; l4[1] = l;
    fsplit(v.z, h, l); h4[2] = h; l4[2] = l;
    fsplit(v.w, h, l); h4[3] = h; l4[3] = l;
    *reinterpret_cast<f16x4*>(&Wh[idx]) = h4;
    *reinterpret_cast<f16x4*>(&Wl[idx]) = l4;
}

// ---------------------------------------------------------------------------
// K1: srcT[b][i][s] = sum_c W[i][c] * ctx[b][c][s]  -- 3-term split-fp16 MFMA
// RE-TILED for occupancy: 128i x 64s, grid (Sn/64, IDF/128, Bn) = 1024 blocks
// -> 4 blocks/CU (16 waves, was 2 blocks/8 waves). LDS 32K: W 16K (wave-
// private slices, gll16 restage) + ctx dbuf 2x8K. Same 3-term math, same
// t-ordering -> outputs bit-identical to round 10.
// ---------------------------------------------------------------------------
__global__ __launch_bounds__(256) void k_srcT(const f16* __restrict__ Wh,
                                              const f16* __restrict__ Wl,
                                              const float* __restrict__ ctx,
                                              f16* __restrict__ si_h,
                                              f16* __restrict__ is_h) {
    // LDS: Wh [128][64B] @0 (8192), Wl @8192 (8192)
    //      ctx dbuf: buf x @16384+x*8192 { Ch [64][64B] (4096), Cl @+4096 }
    //      epilogue: is-transpose [128][128B] (16K) reuses @0
    __shared__ alignas(16) char smem[32768];
    const int tid = threadIdx.x;
    const int w = tid >> 6, lane = tid & 63, g = lane >> 4, l15 = lane & 15;
    const int rxor = ((l15 >> 1) & 3) << 4;

    // bijective XCD swizzle over 1024 blocks (1024 % 8 == 0)
    const int lin = (blockIdx.z * 8 + blockIdx.y) * 4 + blockIdx.x;
    const int swz = (lin & 7) * 128 + (lin >> 3);
    const int b = swz >> 5, rr = swz & 31;
    const int i0 = (rr >> 2) * 128, s0 = (rr & 3) * 64;

    const float* Cp = ctx + (size_t)b * CDF * Sn + s0;
    const int sl = tid & 63, ch = tid >> 6;      // ctx staging: s col, c-chunk(8)
    const int swzw = ((sl >> 1) & 3) << 4;       // ctx write-side XOR (row = sl)

    f32x4 acc[2][4];
    {
        f32x4 z = {0.f, 0.f, 0.f, 0.f};
        #pragma unroll
        for (int mf = 0; mf < 2; ++mf)
            #pragma unroll
            for (int nf = 0; nf < 4; ++nf)
                acc[mf][nf] = z;
    }

    // ---- prologue: W tile 0 (wave-private slice) + ctx tile 0 -> buf0 ----
    #pragma unroll
    for (int part = 0; part < 2; ++part) {
        const int byt = w * 2048 + part * 1024 + lane * 16;
        const int rw = byt >> 6;
        const int co = ((((byt >> 4) & 3) ^ ((rw >> 1) & 3)) << 3);
        const size_t go = (size_t)(i0 + rw) * CDF + co;
        gll16(Wh + go, smem + w * 2048 + part * 1024);
        gll16(Wl + go, smem + 8192 + w * 2048 + part * 1024);
    }
    {
        float cv[8];
        #pragma unroll
        for (int j = 0; j < 8; ++j)
            cv[j] = Cp[(size_t)(ch * 8 + j) * Sn + sl];
        f16x8 h0, l0;
        #pragma unroll
        for (int j = 0; j < 8; ++j) { f16 h, l; fsplit(cv[j], h, l); h0[j] = h; l0[j] = l; }
        char* cb = smem + 16384 + sl * 64;
        *reinterpret_cast<f16x8*>(cb + ((ch * 16) ^ swzw))        = h0;
        *reinterpret_cast<f16x8*>(cb + 4096 + ((ch * 16) ^ swzw)) = l0;
    }
    __syncthreads();

    for (int t = 0; t < 32; ++t) {
        const int kk = t * 32;
        // ---- W frag ds_reads (must complete before re-staging same slice) ----
        f16x8 fwh[2], fwl[2];
        #pragma unroll
        for (int mf = 0; mf < 2; ++mf) {
            const int row = w * 32 + mf * 16 + l15;
            fwh[mf] = *reinterpret_cast<const f16x8*>(smem + row * 64 + ((g * 16) ^ rxor));
            fwl[mf] = *reinterpret_cast<const f16x8*>(smem + 8192 + row * 64 + ((g * 16) ^ rxor));
        }
        asm volatile("s_waitcnt lgkmcnt(0)" ::: "memory");
        __builtin_amdgcn_sched_barrier(0);
        float cv[8];
        if (t < 31) {
            // W(t+1) gll16 into own slice (async, lands under MFMA)
            #pragma unroll
            for (int part = 0; part < 2; ++part) {
                const int byt = w * 2048 + part * 1024 + lane * 16;
                const int rw = byt >> 6;
                const int co = ((((byt >> 4) & 3) ^ ((rw >> 1) & 3)) << 3);
                const size_t go = (size_t)(i0 + rw) * CDF + kk + 32 + co;
                gll16(Wh + go, smem + w * 2048 + part * 1024);
                gll16(Wl + go, smem + 8192 + w * 2048 + part * 1024);
            }
            // ctx(t+1) fp32 prefetch
            #pragma unroll
            for (int j = 0; j < 8; ++j)
                cv[j] = Cp[(size_t)(kk + 32 + ch * 8 + j) * Sn + sl];
        }
        const char* cbuf = smem + 16384 + (t & 1) * 8192;
        __builtin_amdgcn_s_setprio(1);
        #pragma unroll
        for (int nf = 0; nf < 4; ++nf) {
            const int srow = nf * 16 + l15;
            const f16x8 fch = *reinterpret_cast<const f16x8*>(cbuf + srow * 64 + ((g * 16) ^ rxor));
            const f16x8 fcl = *reinterpret_cast<const f16x8*>(cbuf + 4096 + srow * 64 + ((g * 16) ^ rxor));
            #pragma unroll
            for (int mf = 0; mf < 2; ++mf) {
                acc[mf][nf] = __builtin_amdgcn_mfma_f32_16x16x32_f16(fwh[mf], fch, acc[mf][nf], 0, 0, 0);
                acc[mf][nf] = __builtin_amdgcn_mfma_f32_16x16x32_f16(fwh[mf], fcl, acc[mf][nf], 0, 0, 0);
                acc[mf][nf] = __builtin_amdgcn_mfma_f32_16x16x32_f16(fwl[mf], fch, acc[mf][nf], 0, 0, 0);
            }
        }
        __builtin_amdgcn_s_setprio(0);
        if (t < 31) {
            f16x8 h0, l0;
            #pragma unroll
            for (int j = 0; j < 8; ++j) { f16 h, l; fsplit(cv[j], h, l); h0[j] = h; l0[j] = l; }
            char* cb = smem + 16384 + ((t + 1) & 1) * 8192 + sl * 64;
            *reinterpret_cast<f16x8*>(cb + ((ch * 16) ^ swzw))        = h0;
            *reinterpret_cast<f16x8*>(cb + 4096 + ((ch * 16) ^ swzw)) = l0;
        }
        __syncthreads();
    }

    // ---- epilogue 1: si_h (s-major) direct f16x4 stores ----
    #pragma unroll
    for (int mf = 0; mf < 2; ++mf)
        #pragma unroll
        for (int nf = 0; nf < 4; ++nf) {
            f16x4 h4;
            #pragma unroll
            for (int r = 0; r < 4; ++r) h4[r] = (f16)acc[mf][nf][r];
            const int s  = s0 + nf * 16 + l15;
            const int ib = i0 + w * 32 + mf * 16 + g * 4;
            const size_t so = ((size_t)b * Sn + s) * IDF + ib;
            *reinterpret_cast<f16x4*>(&si_h[so]) = h4;
        }

    // ---- epilogue 2: is_h (i-major) via single-pass XOR-swizzled transpose ----
    __syncthreads();
    #pragma unroll
    for (int mf = 0; mf < 2; ++mf) {
        const int ibase = w * 32 + mf * 16 + g * 4;
        #pragma unroll
        for (int nf = 0; nf < 4; ++nf) {
            const int sl2 = nf * 16 + l15;
            #pragma unroll
            for (int r = 0; r < 4; ++r) {
                const int row = ibase + r;
                const int byo = (sl2 * 2) ^ ((row & 7) << 4);
                *reinterpret_cast<f16*>(smem + row * 128 + byo) = (f16)acc[mf][nf][r];
            }
        }
    }
    __syncthreads();
    #pragma unroll
    for (int k = 0; k < 4; ++k) {
        const int c = tid + 256 * k;                   // 0..1023
        const int row = c >> 3, sc = (c & 7) * 8;      // 128 rows x 8-s chunks
        const int byo = (sc * 2) ^ ((row & 7) << 4);
        const f16x8 vh = *reinterpret_cast<const f16x8*>(smem + row * 128 + byo);
        const size_t o = ((size_t)b * IDF + i0 + row) * Sn + s0 + sc;
        *reinterpret_cast<f16x8*>(&is_h[o]) = vh;
    }
}

// ---------------------------------------------------------------------------
// K2: logits via 2-TERM split-fp16 MFMA + fused masked softmax
// (unchanged from round 10)
// ---------------------------------------------------------------------------
__global__ __launch_bounds__(256) void k_attn(const float* __restrict__ inp,
                                              const f16* __restrict__ si_h,
                                              const int* __restrict__ mask,
                                              float* __restrict__ out1,
                                              f16* __restrict__ Ph) {
    __shared__ alignas(16) char smem[36864];
    const int tid = threadIdx.x;
    const int w = tid >> 6, lane = tid & 63, g = lane >> 4, l15 = lane & 15;
    const int rxor = ((l15 >> 1) & 3) << 4;
    const int awz  = ((lane >> 1) & 3) << 4;

    const int lin = blockIdx.y * 36 + blockIdx.x;
    const int swzb = (lin & 7) * 144 + (lin >> 3);
    const int b = swzb / 36, qt = swzb - b * 36;
    const int q0 = qt * 64;

    const float* Ap = inp + (size_t)b * IDF * Qn + q0;
    const f16* BhG = si_h + (size_t)b * Sn * IDF;

    f32x4 acc[4][4];
    {
        f32x4 z = {0.f, 0.f, 0.f, 0.f};
        #pragma unroll
        for (int mf = 0; mf < 4; ++mf)
            #pragma unroll
            for (int nf = 0; nf < 4; ++nf)
                acc[mf][nf] = z;
    }

    #pragma unroll
    for (int it = 0; it < 4; ++it) {
        const int byt = w * 4096 + it * 1024 + lane * 16;
        const int s = byt >> 6;
        const int ko = ((((byt >> 4) & 3) ^ ((s >> 1) & 3)) << 3);
        const size_t go = (size_t)s * IDF + ko;
        gll16(BhG + go, smem + 16384 + w * 4096 + it * 1024);
    }
    {
        float av[8];
        #pragma unroll
        for (int j = 0; j < 8; ++j)
            av[j] = Ap[(size_t)(w * 8 + j) * Qn + lane];
        f16x8 ah, al;
        #pragma unroll
        for (int j = 0; j < 8; ++j) { f16 h, lo; fsplit(av[j], h, lo); ah[j] = h; al[j] = lo; }
        *reinterpret_cast<f16x8*>(smem + lane * 64 + ((w * 16) ^ awz)) = ah;
        *reinterpret_cast<f16x8*>(smem + 4096 + lane * 64 + ((w * 16) ^ awz)) = al;
    }
    __syncthreads();

    for (int t = 0; t < 32; ++t) {
        const int kk = t * 32;
        f16x8 fbh[4];
        #pragma unroll
        for (int nf = 0; nf < 4; ++nf) {
            const int row = w * 64 + nf * 16 + l15;
            fbh[nf] = *reinterpret_cast<const f16x8*>(smem + 16384 + row * 64 + ((g * 16) ^ rxor));
        }
        asm volatile("s_waitcnt lgkmcnt(0)" ::: "memory");
        __builtin_amdgcn_sched_barrier(0);
        float av[8];
        if (t < 31) {
            #pragma unroll
            for (int it = 0; it < 4; ++it) {
                const int byt = w * 4096 + it * 1024 + lane * 16;
                const int s = byt >> 6;
                const int ko = ((((byt >> 4) & 3) ^ ((s >> 1) & 3)) << 3);
                const size_t go = (size_t)s * IDF + kk + 32 + ko;
                gll16(BhG + go, smem + 16384 + w * 4096 + it * 1024);
            }
            #pragma unroll
            for (int j = 0; j < 8; ++j)
                av[j] = Ap[(size_t)(kk + 32 + w * 8 + j) * Qn + lane];
        }
        const char* ab = smem + (t & 1) * 8192;
        __builtin_amdgcn_s_setprio(1);
        #pragma unroll
        for (int mf = 0; mf < 4; ++mf) {
            const f16x8 fah = *reinterpret_cast<const f16x8*>(ab + (mf * 16 + l15) * 64 + ((g * 16) ^ rxor));
            const f16x8 fal = *reinterpret_cast<const f16x8*>(ab + 4096 + (mf * 16 + l15) * 64 + ((g * 16) ^ rxor));
            #pragma unroll
            for (int nf = 0; nf < 4; ++nf) {
                acc[mf][nf] = __builtin_amdgcn_mfma_f32_16x16x32_f16(fah, fbh[nf], acc[mf][nf], 0, 0, 0);
                acc[mf][nf] = __builtin_amdgcn_mfma_f32_16x16x32_f16(fal, fbh[nf], acc[mf][nf], 0, 0, 0);
            }
        }
        __builtin_amdgcn_s_setprio(0);
        if (t < 31) {
            f16x8 ah, al;
            #pragma unroll
            for (int j = 0; j < 8; ++j) { f16 h, lo; fsplit(av[j], h, lo); ah[j] = h; al[j] = lo; }
            char* wb = smem + ((t + 1) & 1) * 8192;
            *reinterpret_cast<f16x8*>(wb + lane * 64 + ((w * 16) ^ awz)) = ah;
            *reinterpret_cast<f16x8*>(wb + 4096 + lane * 64 + ((w * 16) ^ awz)) = al;
        }
        __syncthreads();
    }

    int mv[2][4][4];
    #pragma unroll
    for (int h2 = 0; h2 < 2; ++h2)
        #pragma unroll
        for (int r = 0; r < 4; ++r)
            #pragma unroll
            for (int nf = 0; nf < 4; ++nf)
                mv[h2][r][nf] = mask[(h2 * 16 + g * 4 + r) * Sn + w * 64 + nf * 16 + l15];

    float* redm = reinterpret_cast<float*>(smem + 34816);
    float* reds = reinterpret_cast<float*>(smem + 35840);

    float mx[4][4], sm[4][4];
    #pragma unroll
    for (int mf = 0; mf < 4; ++mf)
        #pragma unroll
        for (int r = 0; r < 4; ++r) {
            float m = -3.0e38f;
            #pragma unroll
            for (int nf = 0; nf < 4; ++nf)
                if (!mv[mf & 1][r][nf]) m = fmaxf(m, acc[mf][nf][r]);
            m = fmaxf(m, __shfl_xor(m, 1, 64));
            m = fmaxf(m, __shfl_xor(m, 2, 64));
            m = fmaxf(m, __shfl_xor(m, 4, 64));
            m = fmaxf(m, __shfl_xor(m, 8, 64));
            mx[mf][r] = m;
        }
    if (l15 == 0) {
        #pragma unroll
        for (int mf = 0; mf < 4; ++mf)
            #pragma unroll
            for (int r = 0; r < 4; ++r)
                redm[w * 64 + mf * 16 + g * 4 + r] = mx[mf][r];
    }
    __syncthreads();
    #pragma unroll
    for (int mf = 0; mf < 4; ++mf)
        #pragma unroll
        for (int r = 0; r < 4; ++r) {
            const int q = mf * 16 + g * 4 + r;
            const float gm = fmaxf(fmaxf(redm[q], redm[64 + q]), fmaxf(redm[128 + q], redm[192 + q]));
            float ssum = 0.f;
            #pragma unroll
            for (int nf = 0; nf < 4; ++nf) {
                const float p = mv[mf & 1][r][nf] ? 0.f : __expf(acc[mf][nf][r] - gm);
                acc[mf][nf][r] = p;
                ssum += p;
            }
            ssum += __shfl_xor(ssum, 1, 64);
            ssum += __shfl_xor(ssum, 2, 64);
            ssum += __shfl_xor(ssum, 4, 64);
            ssum += __shfl_xor(ssum, 8, 64);
            sm[mf][r] = ssum;
        }
    if (l15 == 0) {
        #pragma unroll
        for (int mf = 0; mf < 4; ++mf)
            #pragma unroll
            for (int r = 0; r < 4; ++r)
                reds[w * 64 + mf * 16 + g * 4 + r] = sm[mf][r];
    }
    __syncthreads();
    #pragma unroll
    for (int mf = 0; mf < 4; ++mf)
        #pragma unroll
        for (int r = 0; r < 4; ++r) {
            const int q = mf * 16 + g * 4 + r;
            const float inv = 1.0f / (reds[q] + reds[64 + q] + reds[128 + q] + reds[192 + q]);
            #pragma unroll
            for (int nf = 0; nf < 4; ++nf)
                acc[mf][nf][r] *= inv;
        }

    float* Pl = reinterpret_cast<float*>(smem);
    float* O1 = out1 + (size_t)b * Sn * Qn + q0;
    f16* PhB = Ph + ((size_t)b * Qn + q0) * Sn;
    #pragma unroll
    for (int hf = 0; hf < 2; ++hf) {
        __syncthreads();
        if ((w >> 1) == hf) {
            #pragma unroll
            for (int mf = 0; mf < 4; ++mf)
                #pragma unroll
                for (int nf = 0; nf < 4; ++nf)
                    *reinterpret_cast<f32x4*>(
                        &Pl[((w & 1) * 64 + nf * 16 + l15) * 68 + mf * 16 + g * 4]) = acc[mf][nf];
        }
        __syncthreads();
        #pragma unroll
        for (int j = 0; j < 8; ++j) {
            const int sr = (tid >> 4) + j * 16;
            const int u  = (tid & 15) * 4;
            const f32x4 v = *reinterpret_cast<const f32x4*>(&Pl[sr * 68 + u]);
            *reinterpret_cast<f32x4*>(&O1[(size_t)(hf * 128 + sr) * Qn + u]) = v;
        }
        #pragma unroll
        for (int j = 0; j < 16; ++j) {
            const int colU = l15 + 16 * (j & 3);
            const int q    = (w * 4 + g) + 16 * (j >> 2);
            const float p0 = Pl[(2 * colU) * 68 + q];
            const float p1 = Pl[(2 * colU + 1) * 68 + q];
            f16x2 hh; hh[0] = (f16)p0; hh[1] = (f16)p1;
            *reinterpret_cast<f16x2*>(&PhB[(size_t)q * Sn + hf * 128 + 2 * colU]) = hh;
        }
    }
}

// ---------------------------------------------------------------------------
// K3: out0[b][i][q] = sum_s srcT[b][i][s] * P[b][q][s]   (1-term, unchanged)
// ---------------------------------------------------------------------------
__global__ __launch_bounds__(256) void k_wc(const f16* __restrict__ is_h,
                                            const f16* __restrict__ Ph,
                                            float* __restrict__ out0) {
    __shared__ alignas(16) char smem[32768];
    const int tid = threadIdx.x;
    const int w = tid >> 6, lane = tid & 63, g = lane >> 4, l15 = lane & 15;
    const int wi = w >> 1, wq = w & 1;
    const int rxor = ((l15 >> 1) & 3) << 4;

    const int lin = (blockIdx.z * 8 + blockIdx.y) * 18 + blockIdx.x;
    const int swz = (lin & 7) * 576 + (lin >> 3);
    const int b = swz / 144;
    const int rr = swz - b * 144;
    const int it = rr / 18, qt = rr - it * 18;
    const int i0 = it * 128, q0 = qt * 128;

    const f16* AhG = is_h + ((size_t)b * IDF + i0) * Sn;
    const f16* BG  = Ph  + ((size_t)b * Qn + q0) * Sn;

    f32x4 acc[4][4];
    {
        f32x4 z = {0.f, 0.f, 0.f, 0.f};
        #pragma unroll
        for (int mf = 0; mf < 4; ++mf)
            #pragma unroll
            for (int nf = 0; nf < 4; ++nf)
                acc[mf][nf] = z;
    }

    #pragma unroll
    for (int t2 = 0; t2 < 2; ++t2) {
        const int byt = (w * 2 + t2) * 1024 + lane * 16;
        const int rw = byt >> 6;
        const int so = ((((byt >> 4) & 3) ^ ((rw >> 1) & 3)) << 3);
        const size_t go = (size_t)rw * Sn + so;
        gll16(AhG + go, smem + (w * 2 + t2) * 1024);
        gll16(BG  + go, smem + 8192 + (w * 2 + t2) * 1024);
    }
    __syncthreads();

    for (int t = 0; t < 8; ++t) {
        const int kk = t * 32;
        if (t < 7) {
            #pragma unroll
            for (int t2 = 0; t2 < 2; ++t2) {
                const int byt = (w * 2 + t2) * 1024 + lane * 16;
                const int rw = byt >> 6;
                const int so = ((((byt >> 4) & 3) ^ ((rw >> 1) & 3)) << 3);
                const size_t go = (size_t)rw * Sn + kk + 32 + so;
                char* dst = smem + ((t + 1) & 1) * 16384 + (w * 2 + t2) * 1024;
                gll16(AhG + go, dst);
                gll16(BG  + go, dst + 8192);
            }
        }
        const char* buf = smem + (t & 1) * 16384;
        f16x8 fah[4];
        #pragma unroll
        for (int mf = 0; mf < 4; ++mf) {
            const int row = wi * 64 + mf * 16 + l15;
            fah[mf] = *reinterpret_cast<const f16x8*>(buf + row * 64 + ((g * 16) ^ rxor));
        }
        __builtin_amdgcn_s_setprio(1);
        #pragma unroll
        for (int nf = 0; nf < 4; ++nf) {
            const int row = wq * 64 + nf * 16 + l15;
            const f16x8 fbh = *reinterpret_cast<const f16x8*>(buf + 8192 + row * 64 + ((g * 16) ^ rxor));
            #pragma unroll
            for (int mf = 0; mf < 4; ++mf)
                acc[mf][nf] = __builtin_amdgcn_mfma_f32_16x16x32_f16(fah[mf], fbh, acc[mf][nf], 0, 0, 0);
        }
        __builtin_amdgcn_s_setprio(0);
        __syncthreads();
    }
    float* O = out0 + ((size_t)b * IDF + i0 + wi * 64) * Qn + q0 + wq * 64;
    #pragma unroll
    for (int mf = 0; mf < 4; ++mf)
        #pragma unroll
        for (int nf = 0; nf < 4; ++nf)
            #pragma unroll
            for (int r = 0; r < 4; ++r)
                O[(size_t)(mf * 16 + g * 4 + r) * Qn + nf * 16 + l15] = acc[mf][nf][r];
}

extern "C" void kernel_launch(void* const* d_in, const int* in_sizes, int n_in,
                              void* d_out, int out_size, void* d_ws, size_t ws_size,
                              hipStream_t stream) {
    const float* inp  = (const float*)d_in[0];   // [B, IDF, 48, 48]
    const float* ctx  = (const float*)d_in[1];   // [B, CDF, S]
    const int*   mask = (const int*)  d_in[2];   // [B, S]
    const float* W    = (const float*)d_in[3];   // [IDF, CDF]
    float* out0 = (float*)d_out;                             // weightedContext
    float* out1 = out0 + (size_t)Bn * IDF * Qn;              // attn_out = P^T

    char* ws = (char*)d_ws;
    const size_t SZ = (size_t)Bn * Sn * IDF * sizeof(f16);   // 16 MiB
    f16* si_h = (f16*)(ws);
    f16* is_h = (f16*)(ws + 2 * SZ);
    f16* Ph   = (f16*)(ws + 4 * SZ);                         // [B][Q][S] fp16
    // W hi/lo alias the Ph region (dead until k_attn; k_srcT completes first)
    f16* Wh   = (f16*)(ws + 4 * SZ);
    f16* Wl   = Wh + (size_t)IDF * CDF;

    hipLaunchKernelGGL(k_wsplit, dim3(IDF * CDF / 1024), dim3(256), 0, stream, W, Wh, Wl);
    hipLaunchKernelGGL(k_srcT, dim3(Sn / 64, IDF / 128, Bn), dim3(256), 0, stream,
                       Wh, Wl, ctx, si_h, is_h);
    hipLaunchKernelGGL(k_attn, dim3(Qn / 64, Bn), dim3(256), 0, stream,
                       inp, si_h, mask, out1, Ph);
    hipLaunchKernelGGL(k_wc, dim3(Qn / 128, IDF / 128, Bn), dim3(256), 0, stream,
                       is_h, Ph, out0);
}

// Round 12
// 322.072 us; speedup vs baseline: 1.0338x; 1.0338x over previous
//
#include <hip/hip_runtime.h>

#define Bn  32
#define IDF 1024
#define CDF 1024
#define Qn  2304
#define Sn  256

typedef _Float16 f16;
typedef _Float16 f16x2 __attribute__((ext_vector_type(2)));
typedef _Float16 f16x4 __attribute__((ext_vector_type(4)));
typedef _Float16 f16x8 __attribute__((ext_vector_type(8)));
typedef float    f32x4 __attribute__((ext_vector_type(4)));

// async global->LDS, 16B per lane; dest = wave-uniform base + lane*16
__device__ __forceinline__ void gll16(const void* g, void* l) {
    __builtin_amdgcn_global_load_lds((const __attribute__((address_space(1))) void*)g,
                                     (__attribute__((address_space(3))) void*)l, 16, 0, 0);
}

// split fp32 into fp16 hi + fp16 lo (x ~= hi + lo, error ~2^-23*|x|)
__device__ __forceinline__ void fsplit(float x, f16& hi, f16& lo) {
    hi = (f16)x;
    lo = (f16)(x - (float)hi);
}

// ---------------------------------------------------------------------------
// K0: split W into fp16 hi/lo (runs once, ~4 MB traffic)
// ---------------------------------------------------------------------------
__global__ __launch_bounds__(256) void k_wsplit(const float* __restrict__ W,
                                                f16* __restrict__ Wh, f16* __restrict__ Wl) {
    const int idx = (blockIdx.x * 256 + threadIdx.x) * 4;
    const float4 v = *reinterpret_cast<const float4*>(&W[idx]);
    f16x4 h4, l4;
    f16 h, l;
    fsplit(v.x, h, l); h4[0] = h; l4[0] = l;
    fsplit(v.y, h, l); h4[1] = h; l4[1] = l;
    fsplit(v.z, h, l); h4[2] = h; l4[2] = l;
    fsplit(v.w, h, l); h4[3] = h; l4[3] = l;
    *reinterpret_cast<f16x4*>(&Wh[idx]) = h4;
    *reinterpret_cast<f16x4*>(&Wl[idx]) = l4;
}

// ---------------------------------------------------------------------------
// K1: srcT[b][i][s] = sum_c W[i][c] * ctx[b][c][s]  -- 3-term split-fp16 MFMA
// (REVERTED to round-10 best: 128i x 128s, wave-private W restage, ctx dbuf)
// outputs: si_h [b][s][IDF], is_h [b][i][Sn] (fp16 hi only)
// ---------------------------------------------------------------------------
__global__ __launch_bounds__(256) void k_srcT(const f16* __restrict__ Wh,
                                              const f16* __restrict__ Wl,
                                              const float* __restrict__ ctx,
                                              f16* __restrict__ si_h,
                                              f16* __restrict__ is_h) {
    __shared__ alignas(16) char smem[49152];
    const int tid = threadIdx.x;
    const int w = tid >> 6, lane = tid & 63, g = lane >> 4, l15 = lane & 15;
    const int rxor = ((l15 >> 1) & 3) << 4;

    const int lin = (blockIdx.z * 8 + blockIdx.y) * 2 + blockIdx.x;
    const int swz = (lin & 7) * 64 + (lin >> 3);
    const int b = swz >> 4, rr = swz & 15;
    const int i0 = (rr >> 1) * 128, s0 = (rr & 1) * 128;

    const float* Cp = ctx + (size_t)b * CDF * Sn + s0;
    const int sl = tid & 127, ch = tid >> 7;
    const int swzw = ((sl >> 1) & 3) << 4;

    f32x4 acc[2][8];
    {
        f32x4 z = {0.f, 0.f, 0.f, 0.f};
        #pragma unroll
        for (int mf = 0; mf < 2; ++mf)
            #pragma unroll
            for (int nf = 0; nf < 8; ++nf)
                acc[mf][nf] = z;
    }

    #pragma unroll
    for (int part = 0; part < 2; ++part) {
        const int byt = w * 2048 + part * 1024 + lane * 16;
        const int rw = byt >> 6;
        const int co = ((((byt >> 4) & 3) ^ ((rw >> 1) & 3)) << 3);
        const size_t go = (size_t)(i0 + rw) * CDF + co;
        gll16(Wh + go, smem + w * 2048 + part * 1024);
        gll16(Wl + go, smem + 8192 + w * 2048 + part * 1024);
    }
    {
        float cv[16];
        #pragma unroll
        for (int j = 0; j < 16; ++j)
            cv[j] = Cp[(size_t)(ch * 16 + j) * Sn + sl];
        f16x8 h0, h1, l0, l1;
        #pragma unroll
        for (int j = 0; j < 8; ++j) { f16 h, l; fsplit(cv[j], h, l); h0[j] = h; l0[j] = l; }
        #pragma unroll
        for (int j = 0; j < 8; ++j) { f16 h, l; fsplit(cv[8 + j], h, l); h1[j] = h; l1[j] = l; }
        char* cb = smem + 16384 + sl * 64;
        *reinterpret_cast<f16x8*>(cb + (((ch * 32) + 0) ^ swzw))        = h0;
        *reinterpret_cast<f16x8*>(cb + (((ch * 32) + 16) ^ swzw))       = h1;
        *reinterpret_cast<f16x8*>(cb + 8192 + (((ch * 32) + 0) ^ swzw)) = l0;
        *reinterpret_cast<f16x8*>(cb + 8192 + (((ch * 32) + 16) ^ swzw))= l1;
    }
    __syncthreads();

    for (int t = 0; t < 32; ++t) {
        const int kk = t * 32;
        f16x8 fwh[2], fwl[2];
        #pragma unroll
        for (int mf = 0; mf < 2; ++mf) {
            const int row = w * 32 + mf * 16 + l15;
            fwh[mf] = *reinterpret_cast<const f16x8*>(smem + row * 64 + ((g * 16) ^ rxor));
            fwl[mf] = *reinterpret_cast<const f16x8*>(smem + 8192 + row * 64 + ((g * 16) ^ rxor));
        }
        asm volatile("s_waitcnt lgkmcnt(0)" ::: "memory");
        __builtin_amdgcn_sched_barrier(0);
        float cv[16];
        if (t < 31) {
            #pragma unroll
            for (int part = 0; part < 2; ++part) {
                const int byt = w * 2048 + part * 1024 + lane * 16;
                const int rw = byt >> 6;
                const int co = ((((byt >> 4) & 3) ^ ((rw >> 1) & 3)) << 3);
                const size_t go = (size_t)(i0 + rw) * CDF + kk + 32 + co;
                gll16(Wh + go, smem + w * 2048 + part * 1024);
                gll16(Wl + go, smem + 8192 + w * 2048 + part * 1024);
            }
            #pragma unroll
            for (int j = 0; j < 16; ++j)
                cv[j] = Cp[(size_t)(kk + 32 + ch * 16 + j) * Sn + sl];
        }
        const char* cbuf = smem + 16384 + (t & 1) * 16384;
        __builtin_amdgcn_s_setprio(1);
        #pragma unroll
        for (int nf = 0; nf < 8; ++nf) {
            const int srow = nf * 16 + l15;
            const f16x8 fch = *reinterpret_cast<const f16x8*>(cbuf + srow * 64 + ((g * 16) ^ rxor));
            const f16x8 fcl = *reinterpret_cast<const f16x8*>(cbuf + 8192 + srow * 64 + ((g * 16) ^ rxor));
            #pragma unroll
            for (int mf = 0; mf < 2; ++mf) {
                acc[mf][nf] = __builtin_amdgcn_mfma_f32_16x16x32_f16(fwh[mf], fch, acc[mf][nf], 0, 0, 0);
                acc[mf][nf] = __builtin_amdgcn_mfma_f32_16x16x32_f16(fwh[mf], fcl, acc[mf][nf], 0, 0, 0);
                acc[mf][nf] = __builtin_amdgcn_mfma_f32_16x16x32_f16(fwl[mf], fch, acc[mf][nf], 0, 0, 0);
            }
        }
        __builtin_amdgcn_s_setprio(0);
        if (t < 31) {
            f16x8 h0, h1, l0, l1;
            #pragma unroll
            for (int j = 0; j < 8; ++j) { f16 h, l; fsplit(cv[j], h, l); h0[j] = h; l0[j] = l; }
            #pragma unroll
            for (int j = 0; j < 8; ++j) { f16 h, l; fsplit(cv[8 + j], h, l); h1[j] = h; l1[j] = l; }
            char* cb = smem + 16384 + ((t + 1) & 1) * 16384 + sl * 64;
            *reinterpret_cast<f16x8*>(cb + (((ch * 32) + 0) ^ swzw))        = h0;
            *reinterpret_cast<f16x8*>(cb + (((ch * 32) + 16) ^ swzw))       = h1;
            *reinterpret_cast<f16x8*>(cb + 8192 + (((ch * 32) + 0) ^ swzw)) = l0;
            *reinterpret_cast<f16x8*>(cb + 8192 + (((ch * 32) + 16) ^ swzw))= l1;
        }
        __syncthreads();
    }

    // ---- epilogue 1: si_h (s-major) direct f16x4 stores ----
    #pragma unroll
    for (int mf = 0; mf < 2; ++mf)
        #pragma unroll
        for (int nf = 0; nf < 8; ++nf) {
            f16x4 h4;
            #pragma unroll
            for (int r = 0; r < 4; ++r) h4[r] = (f16)acc[mf][nf][r];
            const int s  = s0 + nf * 16 + l15;
            const int ib = i0 + w * 32 + mf * 16 + g * 4;
            const size_t so = ((size_t)b * Sn + s) * IDF + ib;
            *reinterpret_cast<f16x4*>(&si_h[so]) = h4;
        }

    // ---- epilogue 2: is_h (i-major) via 2-pass XOR-swizzled LDS transpose ----
    #pragma unroll
    for (int p = 0; p < 2; ++p) {
        __syncthreads();
        #pragma unroll
        for (int mf = 0; mf < 2; ++mf) {
            const int ibase = w * 32 + mf * 16 + g * 4;
            #pragma unroll
            for (int nf4 = 0; nf4 < 4; ++nf4) {
                const int sl2 = nf4 * 16 + l15;
                #pragma unroll
                for (int r = 0; r < 4; ++r) {
                    const int row = ibase + r;
                    const int byo = (sl2 * 2) ^ ((row & 7) << 4);
                    *reinterpret_cast<f16*>(smem + row * 128 + byo) = (f16)acc[mf][p * 4 + nf4][r];
                }
            }
        }
        __syncthreads();
        #pragma unroll
        for (int k = 0; k < 4; ++k) {
            const int c = tid + 256 * k;
            const int row = c >> 3, sc = (c & 7) * 8;
            const int byo = (sc * 2) ^ ((row & 7) << 4);
            const f16x8 vh = *reinterpret_cast<const f16x8*>(smem + row * 128 + byo);
            const size_t o = ((size_t)b * IDF + i0 + row) * Sn + s0 + p * 64 + sc;
            *reinterpret_cast<f16x8*>(&is_h[o]) = vh;
        }
    }
}

// ---------------------------------------------------------------------------
// K2: logits via 2-TERM split-fp16 MFMA + fused masked softmax
// MERGED: round-8's 128q x 64s per-wave tile (mf=8: 3.2 MFMA/ds_read, was
// 2.67) + round-10's 2-term B (Bh only). LDS 48K -> 3 blocks/CU (12 waves).
// grid (Qn/128, Bn), block 256 (4 waves 1x4 over s).
// LDS: A dbuf 2 x { Ah[128][64B] 8K + Al 8K } @0..32768; Bh[256][64B] @32768
// epilogue union: Pl f32 [64][132] @0, redm @34816, reds @36864
// ---------------------------------------------------------------------------
__global__ __launch_bounds__(256, 2) void k_attn(const float* __restrict__ inp,
                                                 const f16* __restrict__ si_h,
                                                 const int* __restrict__ mask,
                                                 float* __restrict__ out1,
                                                 f16* __restrict__ Ph) {
    __shared__ alignas(16) char smem[49152];
    const int tid = threadIdx.x;
    const int w = tid >> 6, lane = tid & 63, g = lane >> 4, l15 = lane & 15;
    const int rxor = ((l15 >> 1) & 3) << 4;

    // bijective XCD swizzle over 576 blocks (576 % 8 == 0)
    const int lin = blockIdx.y * 18 + blockIdx.x;
    const int swzb = (lin & 7) * 72 + (lin >> 3);
    const int b = swzb / 18, qt = swzb - b * 18;
    const int q0 = qt * 128;

    const float* Ap = inp + (size_t)b * IDF * Qn + q0;
    const f16* BhG = si_h + (size_t)b * Sn * IDF;

    // A staging: thread handles q col sl (0..127), k-chunk ch (0..1)
    const int sl = tid & 127, ch = tid >> 7;
    const int swzw = ((sl >> 1) & 3) << 4;

    f32x4 acc[8][4];
    {
        f32x4 z = {0.f, 0.f, 0.f, 0.f};
        #pragma unroll
        for (int mf = 0; mf < 8; ++mf)
            #pragma unroll
            for (int nf = 0; nf < 4; ++nf)
                acc[mf][nf] = z;
    }

    // ---- prologue: B tile 0 (wave slice) + A tile 0 -> buf0 ----
    #pragma unroll
    for (int it = 0; it < 4; ++it) {
        const int byt = w * 4096 + it * 1024 + lane * 16;
        const int s = byt >> 6;
        const int ko = ((((byt >> 4) & 3) ^ ((s >> 1) & 3)) << 3);
        const size_t go = (size_t)s * IDF + ko;
        gll16(BhG + go, smem + 32768 + w * 4096 + it * 1024);
    }
    {
        float cv[16];
        #pragma unroll
        for (int j = 0; j < 16; ++j)
            cv[j] = Ap[(size_t)(ch * 16 + j) * Qn + sl];
        f16x8 h0, h1, l0, l1;
        #pragma unroll
        for (int j = 0; j < 8; ++j) { f16 h, l; fsplit(cv[j], h, l); h0[j] = h; l0[j] = l; }
        #pragma unroll
        for (int j = 0; j < 8; ++j) { f16 h, l; fsplit(cv[8 + j], h, l); h1[j] = h; l1[j] = l; }
        char* cb = smem + sl * 64;
        *reinterpret_cast<f16x8*>(cb + (((ch * 32) + 0) ^ swzw))        = h0;
        *reinterpret_cast<f16x8*>(cb + (((ch * 32) + 16) ^ swzw))       = h1;
        *reinterpret_cast<f16x8*>(cb + 8192 + (((ch * 32) + 0) ^ swzw)) = l0;
        *reinterpret_cast<f16x8*>(cb + 8192 + (((ch * 32) + 16) ^ swzw))= l1;
    }
    __syncthreads();

    for (int t = 0; t < 32; ++t) {
        const int kk = t * 32;
        // ---- B frag ds_reads (must complete before re-staging same slice) ----
        f16x8 fbh[4];
        #pragma unroll
        for (int nf = 0; nf < 4; ++nf) {
            const int row = w * 64 + nf * 16 + l15;
            fbh[nf] = *reinterpret_cast<const f16x8*>(smem + 32768 + row * 64 + ((g * 16) ^ rxor));
        }
        asm volatile("s_waitcnt lgkmcnt(0)" ::: "memory");
        __builtin_amdgcn_sched_barrier(0);
        float cv[16];
        if (t < 31) {
            // B(t+1) gll16 into own slice (async, lands under MFMA)
            #pragma unroll
            for (int it = 0; it < 4; ++it) {
                const int byt = w * 4096 + it * 1024 + lane * 16;
                const int s = byt >> 6;
                const int ko = ((((byt >> 4) & 3) ^ ((s >> 1) & 3)) << 3);
                const size_t go = (size_t)s * IDF + kk + 32 + ko;
                gll16(BhG + go, smem + 32768 + w * 4096 + it * 1024);
            }
            // A(t+1) fp32 prefetch
            #pragma unroll
            for (int j = 0; j < 16; ++j)
                cv[j] = Ap[(size_t)(kk + 32 + ch * 16 + j) * Qn + sl];
        }
        // ---- MFMA (2-term), A frags from buf[t&1], 8 mf x 4 nf ----
        const char* ab = smem + (t & 1) * 16384;
        __builtin_amdgcn_s_setprio(1);
        #pragma unroll
        for (int mf = 0; mf < 8; ++mf) {
            const f16x8 fah = *reinterpret_cast<const f16x8*>(ab + (mf * 16 + l15) * 64 + ((g * 16) ^ rxor));
            const f16x8 fal = *reinterpret_cast<const f16x8*>(ab + 8192 + (mf * 16 + l15) * 64 + ((g * 16) ^ rxor));
            #pragma unroll
            for (int nf = 0; nf < 4; ++nf) {
                acc[mf][nf] = __builtin_amdgcn_mfma_f32_16x16x32_f16(fah, fbh[nf], acc[mf][nf], 0, 0, 0);
                acc[mf][nf] = __builtin_amdgcn_mfma_f32_16x16x32_f16(fal, fbh[nf], acc[mf][nf], 0, 0, 0);
            }
        }
        __builtin_amdgcn_s_setprio(0);
        // ---- split + write A(t+1) into other buffer ----
        if (t < 31) {
            f16x8 h0, h1, l0, l1;
            #pragma unroll
            for (int j = 0; j < 8; ++j) { f16 h, l; fsplit(cv[j], h, l); h0[j] = h; l0[j] = l; }
            #pragma unroll
            for (int j = 0; j < 8; ++j) { f16 h, l; fsplit(cv[8 + j], h, l); h1[j] = h; l1[j] = l; }
            char* cb = smem + ((t + 1) & 1) * 16384 + sl * 64;
            *reinterpret_cast<f16x8*>(cb + (((ch * 32) + 0) ^ swzw))        = h0;
            *reinterpret_cast<f16x8*>(cb + (((ch * 32) + 16) ^ swzw))       = h1;
            *reinterpret_cast<f16x8*>(cb + 8192 + (((ch * 32) + 0) ^ swzw)) = l0;
            *reinterpret_cast<f16x8*>(cb + 8192 + (((ch * 32) + 16) ^ swzw))= l1;
        }
        __syncthreads();
    }

    // ---- masked softmax over s (q = mf*16 + g*4 + r; q%32 = (mf&1)*16+g*4+r) ----
    int mv[2][4][4];
    #pragma unroll
    for (int h2 = 0; h2 < 2; ++h2)
        #pragma unroll
        for (int r = 0; r < 4; ++r)
            #pragma unroll
            for (int nf = 0; nf < 4; ++nf)
                mv[h2][r][nf] = mask[(h2 * 16 + g * 4 + r) * Sn + w * 64 + nf * 16 + l15];

    float* redm = reinterpret_cast<float*>(smem + 34816);   // [4 waves][128 q]
    float* reds = reinterpret_cast<float*>(smem + 36864);

    float mx[8][4], sm[8][4];
    #pragma unroll
    for (int mf = 0; mf < 8; ++mf)
        #pragma unroll
        for (int r = 0; r < 4; ++r) {
            float m = -3.0e38f;
            #pragma unroll
            for (int nf = 0; nf < 4; ++nf)
                if (!mv[mf & 1][r][nf]) m = fmaxf(m, acc[mf][nf][r]);
            m = fmaxf(m, __shfl_xor(m, 1, 64));
            m = fmaxf(m, __shfl_xor(m, 2, 64));
            m = fmaxf(m, __shfl_xor(m, 4, 64));
            m = fmaxf(m, __shfl_xor(m, 8, 64));
            mx[mf][r] = m;
        }
    if (l15 == 0) {
        #pragma unroll
        for (int mf = 0; mf < 8; ++mf)
            #pragma unroll
            for (int r = 0; r < 4; ++r)
                redm[w * 128 + mf * 16 + g * 4 + r] = mx[mf][r];
    }
    __syncthreads();
    #pragma unroll
    for (int mf = 0; mf < 8; ++mf)
        #pragma unroll
        for (int r = 0; r < 4; ++r) {
            const int q = mf * 16 + g * 4 + r;
            const float gm = fmaxf(fmaxf(redm[q], redm[128 + q]), fmaxf(redm[256 + q], redm[384 + q]));
            float ssum = 0.f;
            #pragma unroll
            for (int nf = 0; nf < 4; ++nf) {
                const float p = mv[mf & 1][r][nf] ? 0.f : __expf(acc[mf][nf][r] - gm);
                acc[mf][nf][r] = p;
                ssum += p;
            }
            ssum += __shfl_xor(ssum, 1, 64);
            ssum += __shfl_xor(ssum, 2, 64);
            ssum += __shfl_xor(ssum, 4, 64);
            ssum += __shfl_xor(ssum, 8, 64);
            sm[mf][r] = ssum;
        }
    if (l15 == 0) {
        #pragma unroll
        for (int mf = 0; mf < 8; ++mf)
            #pragma unroll
            for (int r = 0; r < 4; ++r)
                reds[w * 128 + mf * 16 + g * 4 + r] = sm[mf][r];
    }
    __syncthreads();
    #pragma unroll
    for (int mf = 0; mf < 8; ++mf)
        #pragma unroll
        for (int r = 0; r < 4; ++r) {
            const int q = mf * 16 + g * 4 + r;
            const float inv = 1.0f / (reds[q] + reds[128 + q] + reds[256 + q] + reds[384 + q]);
            #pragma unroll
            for (int nf = 0; nf < 4; ++nf)
                acc[mf][nf][r] *= inv;
        }

    // ---- outputs: 4 passes of 64-s slabs; pass p owned by wave p ----
    float* Pl = reinterpret_cast<float*>(smem);              // [64 s][132 f32]
    float* O1 = out1 + (size_t)b * Sn * Qn + q0;
    f16* PhB = Ph + ((size_t)b * Qn + q0) * Sn;
    #pragma unroll
    for (int p = 0; p < 4; ++p) {
        __syncthreads();
        if (w == p) {
            #pragma unroll
            for (int mf = 0; mf < 8; ++mf)
                #pragma unroll
                for (int nf = 0; nf < 4; ++nf)
                    *reinterpret_cast<f32x4*>(
                        &Pl[(nf * 16 + l15) * 132 + mf * 16 + g * 4]) = acc[mf][nf];
        }
        __syncthreads();
        // out1: 64 s x 128 q, coalesced f32x4
        #pragma unroll
        for (int j = 0; j < 8; ++j) {
            const int sr = (tid >> 5) + j * 8;
            const int u  = (tid & 31) * 4;
            const f32x4 v = *reinterpret_cast<const f32x4*>(&Pl[sr * 132 + u]);
            *reinterpret_cast<f32x4*>(&O1[(size_t)(p * 64 + sr) * Qn + u]) = v;
        }
        // Ph: q rows 128, 32 s-pairs
        #pragma unroll
        for (int j = 0; j < 16; ++j) {
            const int colU = l15 + 16 * (j & 1);             // s-pair 0..31
            const int q    = (w * 4 + g) + 16 * (j >> 1);    // 0..127
            const float p0 = Pl[(2 * colU) * 132 + q];
            const float p1 = Pl[(2 * colU + 1) * 132 + q];
            f16x2 hh; hh[0] = (f16)p0; hh[1] = (f16)p1;
            *reinterpret_cast<f16x2*>(&PhB[(size_t)q * Sn + p * 64 + 2 * colU]) = hh;
        }
    }
}

// ---------------------------------------------------------------------------
// K3: out0[b][i][q] = sum_s srcT[b][i][s] * P[b][q][s]   (1-term, unchanged;
// write-roofline-bound at ~57 us)
// ---------------------------------------------------------------------------
__global__ __launch_bounds__(256) void k_wc(const f16* __restrict__ is_h,
                                            const f16* __restrict__ Ph,
                                            float* __restrict__ out0) {
    __shared__ alignas(16) char smem[32768];
    const int tid = threadIdx.x;
    const int w = tid >> 6, lane = tid & 63, g = lane >> 4, l15 = lane & 15;
    const int wi = w >> 1, wq = w & 1;
    const int rxor = ((l15 >> 1) & 3) << 4;

    const int lin = (blockIdx.z * 8 + blockIdx.y) * 18 + blockIdx.x;
    const int swz = (lin & 7) * 576 + (lin >> 3);
    const int b = swz / 144;
    const int rr = swz - b * 144;
    const int it = rr / 18, qt = rr - it * 18;
    const int i0 = it * 128, q0 = qt * 128;

    const f16* AhG = is_h + ((size_t)b * IDF + i0) * Sn;
    const f16* BG  = Ph  + ((size_t)b * Qn + q0) * Sn;

    f32x4 acc[4][4];
    {
        f32x4 z = {0.f, 0.f, 0.f, 0.f};
        #pragma unroll
        for (int mf = 0; mf < 4; ++mf)
            #pragma unroll
            for (int nf = 0; nf < 4; ++nf)
                acc[mf][nf] = z;
    }

    #pragma unroll
    for (int t2 = 0; t2 < 2; ++t2) {
        const int byt = (w * 2 + t2) * 1024 + lane * 16;
        const int rw = byt >> 6;
        const int so = ((((byt >> 4) & 3) ^ ((rw >> 1) & 3)) << 3);
        const size_t go = (size_t)rw * Sn + so;
        gll16(AhG + go, smem + (w * 2 + t2) * 1024);
        gll16(BG  + go, smem + 8192 + (w * 2 + t2) * 1024);
    }
    __syncthreads();

    for (int t = 0; t < 8; ++t) {
        const int kk = t * 32;
        if (t < 7) {
            #pragma unroll
            for (int t2 = 0; t2 < 2; ++t2) {
                const int byt = (w * 2 + t2) * 1024 + lane * 16;
                const int rw = byt >> 6;
                const int so = ((((byt >> 4) & 3) ^ ((rw >> 1) & 3)) << 3);
                const size_t go = (size_t)rw * Sn + kk + 32 + so;
                char* dst = smem + ((t + 1) & 1) * 16384 + (w * 2 + t2) * 1024;
                gll16(AhG + go, dst);
                gll16(BG  + go, dst + 8192);
            }
        }
        const char* buf = smem + (t & 1) * 16384;
        f16x8 fah[4];
        #pragma unroll
        for (int mf = 0; mf < 4; ++mf) {
            const int row = wi * 64 + mf * 16 + l15;
            fah[mf] = *reinterpret_cast<const f16x8*>(buf + row * 64 + ((g * 16) ^ rxor));
        }
        __builtin_amdgcn_s_setprio(1);
        #pragma unroll
        for (int nf = 0; nf < 4; ++nf) {
            const int row = wq * 64 + nf * 16 + l15;
            const f16x8 fbh = *reinterpret_cast<const f16x8*>(buf + 8192 + row * 64 + ((g * 16) ^ rxor));
            #pragma unroll
            for (int mf = 0; mf < 4; ++mf)
                acc[mf][nf] = __builtin_amdgcn_mfma_f32_16x16x32_f16(fah[mf], fbh, acc[mf][nf], 0, 0, 0);
        }
        __builtin_amdgcn_s_setprio(0);
        __syncthreads();
    }
    float* O = out0 + ((size_t)b * IDF + i0 + wi * 64) * Qn + q0 + wq * 64;
    #pragma unroll
    for (int mf = 0; mf < 4; ++mf)
        #pragma unroll
        for (int nf = 0; nf < 4; ++nf)
            #pragma unroll
            for (int r = 0; r < 4; ++r)
                O[(size_t)(mf * 16 + g * 4 + r) * Qn + nf * 16 + l15] = acc[mf][nf][r];
}

extern "C" void kernel_launch(void* const* d_in, const int* in_sizes, int n_in,
                              void* d_out, int out_size, void* d_ws, size_t ws_size,
                              hipStream_t stream) {
    const float* inp  = (const float*)d_in[0];   // [B, IDF, 48, 48]
    const float* ctx  = (const float*)d_in[1];   // [B, CDF, S]
    const int*   mask = (const int*)  d_in[2];   // [B, S]
    const float* W    = (const float*)d_in[3];   // [IDF, CDF]
    float* out0 = (float*)d_out;                             // weightedContext
    float* out1 = out0 + (size_t)Bn * IDF * Qn;              // attn_out = P^T

    char* ws = (char*)d_ws;
    const size_t SZ = (size_t)Bn * Sn * IDF * sizeof(f16);   // 16 MiB
    f16* si_h = (f16*)(ws);
    f16* is_h = (f16*)(ws + 2 * SZ);
    f16* Ph   = (f16*)(ws + 4 * SZ);                         // [B][Q][S] fp16
    // W hi/lo alias the Ph region (dead until k_attn; k_srcT completes first)
    f16* Wh   = (f16*)(ws + 4 * SZ);
    f16* Wl   = Wh + (size_t)IDF * CDF;

    hipLaunchKernelGGL(k_wsplit, dim3(IDF * CDF / 1024), dim3(256), 0, stream, W, Wh, Wl);
    hipLaunchKernelGGL(k_srcT, dim3(Sn / 128, IDF / 128, Bn), dim3(256), 0, stream,
                       Wh, Wl, ctx, si_h, is_h);
    hipLaunchKernelGGL(k_attn, dim3(Qn / 128, Bn), dim3(256), 0, stream,
                       inp, si_h, mask, out1, Ph);
    hipLaunchKernelGGL(k_wc, dim3(Qn / 128, IDF / 128, Bn), dim3(256), 0, stream,
                       is_h, Ph, out0);
}

// Round 13
// 318.820 us; speedup vs baseline: 1.0443x; 1.0102x over previous
//
#include <hip/hip_runtime.h>

#define Bn  32
#define IDF 1024
#define CDF 1024
#define Qn  2304
#define Sn  256

typedef _Float16 f16;
typedef _Float16 f16x2 __attribute__((ext_vector_type(2)));
typedef _Float16 f16x4 __attribute__((ext_vector_type(4)));
typedef _Float16 f16x8 __attribute__((ext_vector_type(8)));
typedef float    f32x4 __attribute__((ext_vector_type(4)));

// async global->LDS, 16B per lane; dest = wave-uniform base + lane*16
__device__ __forceinline__ void gll16(const void* g, void* l) {
    __builtin_amdgcn_global_load_lds((const __attribute__((address_space(1))) void*)g,
                                     (__attribute__((address_space(3))) void*)l, 16, 0, 0);
}

// split fp32 into fp16 hi + fp16 lo (x ~= hi + lo, error ~2^-23*|x|)
__device__ __forceinline__ void fsplit(float x, f16& hi, f16& lo) {
    hi = (f16)x;
    lo = (f16)(x - (float)hi);
}

// ---------------------------------------------------------------------------
// K0: split W into fp16 hi/lo (runs once, ~4 MB traffic)
// ---------------------------------------------------------------------------
__global__ __launch_bounds__(256) void k_wsplit(const float* __restrict__ W,
                                                f16* __restrict__ Wh, f16* __restrict__ Wl) {
    const int idx = (blockIdx.x * 256 + threadIdx.x) * 4;
    const float4 v = *reinterpret_cast<const float4*>(&W[idx]);
    f16x4 h4, l4;
    f16 h, l;
    fsplit(v.x, h, l); h4[0] = h; l4[0] = l;
    fsplit(v.y, h, l); h4[1] = h; l4[1] = l;
    fsplit(v.z, h, l); h4[2] = h; l4[2] = l;
    fsplit(v.w, h, l); h4[3] = h; l4[3] = l;
    *reinterpret_cast<f16x4*>(&Wh[idx]) = h4;
    *reinterpret_cast<f16x4*>(&Wl[idx]) = l4;
}

// ---------------------------------------------------------------------------
// K1: srcT[b][i][s] = sum_c W[i][c] * ctx[b][c][s]  -- 3-term split-fp16 MFMA
// (frozen: round-10 best -- 128i x 128s, wave-private W restage, ctx dbuf)
// outputs: si_h [b][s][IDF], is_h [b][i][Sn] (fp16 hi only)
// ---------------------------------------------------------------------------
__global__ __launch_bounds__(256) void k_srcT(const f16* __restrict__ Wh,
                                              const f16* __restrict__ Wl,
                                              const float* __restrict__ ctx,
                                              f16* __restrict__ si_h,
                                              f16* __restrict__ is_h) {
    __shared__ alignas(16) char smem[49152];
    const int tid = threadIdx.x;
    const int w = tid >> 6, lane = tid & 63, g = lane >> 4, l15 = lane & 15;
    const int rxor = ((l15 >> 1) & 3) << 4;

    const int lin = (blockIdx.z * 8 + blockIdx.y) * 2 + blockIdx.x;
    const int swz = (lin & 7) * 64 + (lin >> 3);
    const int b = swz >> 4, rr = swz & 15;
    const int i0 = (rr >> 1) * 128, s0 = (rr & 1) * 128;

    const float* Cp = ctx + (size_t)b * CDF * Sn + s0;
    const int sl = tid & 127, ch = tid >> 7;
    const int swzw = ((sl >> 1) & 3) << 4;

    f32x4 acc[2][8];
    {
        f32x4 z = {0.f, 0.f, 0.f, 0.f};
        #pragma unroll
        for (int mf = 0; mf < 2; ++mf)
            #pragma unroll
            for (int nf = 0; nf < 8; ++nf)
                acc[mf][nf] = z;
    }

    #pragma unroll
    for (int part = 0; part < 2; ++part) {
        const int byt = w * 2048 + part * 1024 + lane * 16;
        const int rw = byt >> 6;
        const int co = ((((byt >> 4) & 3) ^ ((rw >> 1) & 3)) << 3);
        const size_t go = (size_t)(i0 + rw) * CDF + co;
        gll16(Wh + go, smem + w * 2048 + part * 1024);
        gll16(Wl + go, smem + 8192 + w * 2048 + part * 1024);
    }
    {
        float cv[16];
        #pragma unroll
        for (int j = 0; j < 16; ++j)
            cv[j] = Cp[(size_t)(ch * 16 + j) * Sn + sl];
        f16x8 h0, h1, l0, l1;
        #pragma unroll
        for (int j = 0; j < 8; ++j) { f16 h, l; fsplit(cv[j], h, l); h0[j] = h; l0[j] = l; }
        #pragma unroll
        for (int j = 0; j < 8; ++j) { f16 h, l; fsplit(cv[8 + j], h, l); h1[j] = h; l1[j] = l; }
        char* cb = smem + 16384 + sl * 64;
        *reinterpret_cast<f16x8*>(cb + (((ch * 32) + 0) ^ swzw))        = h0;
        *reinterpret_cast<f16x8*>(cb + (((ch * 32) + 16) ^ swzw))       = h1;
        *reinterpret_cast<f16x8*>(cb + 8192 + (((ch * 32) + 0) ^ swzw)) = l0;
        *reinterpret_cast<f16x8*>(cb + 8192 + (((ch * 32) + 16) ^ swzw))= l1;
    }
    __syncthreads();

    for (int t = 0; t < 32; ++t) {
        const int kk = t * 32;
        f16x8 fwh[2], fwl[2];
        #pragma unroll
        for (int mf = 0; mf < 2; ++mf) {
            const int row = w * 32 + mf * 16 + l15;
            fwh[mf] = *reinterpret_cast<const f16x8*>(smem + row * 64 + ((g * 16) ^ rxor));
            fwl[mf] = *reinterpret_cast<const f16x8*>(smem + 8192 + row * 64 + ((g * 16) ^ rxor));
        }
        asm volatile("s_waitcnt lgkmcnt(0)" ::: "memory");
        __builtin_amdgcn_sched_barrier(0);
        float cv[16];
        if (t < 31) {
            #pragma unroll
            for (int part = 0; part < 2; ++part) {
                const int byt = w * 2048 + part * 1024 + lane * 16;
                const int rw = byt >> 6;
                const int co = ((((byt >> 4) & 3) ^ ((rw >> 1) & 3)) << 3);
                const size_t go = (size_t)(i0 + rw) * CDF + kk + 32 + co;
                gll16(Wh + go, smem + w * 2048 + part * 1024);
                gll16(Wl + go, smem + 8192 + w * 2048 + part * 1024);
            }
            #pragma unroll
            for (int j = 0; j < 16; ++j)
                cv[j] = Cp[(size_t)(kk + 32 + ch * 16 + j) * Sn + sl];
        }
        const char* cbuf = smem + 16384 + (t & 1) * 16384;
        __builtin_amdgcn_s_setprio(1);
        #pragma unroll
        for (int nf = 0; nf < 8; ++nf) {
            const int srow = nf * 16 + l15;
            const f16x8 fch = *reinterpret_cast<const f16x8*>(cbuf + srow * 64 + ((g * 16) ^ rxor));
            const f16x8 fcl = *reinterpret_cast<const f16x8*>(cbuf + 8192 + srow * 64 + ((g * 16) ^ rxor));
            #pragma unroll
            for (int mf = 0; mf < 2; ++mf) {
                acc[mf][nf] = __builtin_amdgcn_mfma_f32_16x16x32_f16(fwh[mf], fch, acc[mf][nf], 0, 0, 0);
                acc[mf][nf] = __builtin_amdgcn_mfma_f32_16x16x32_f16(fwh[mf], fcl, acc[mf][nf], 0, 0, 0);
                acc[mf][nf] = __builtin_amdgcn_mfma_f32_16x16x32_f16(fwl[mf], fch, acc[mf][nf], 0, 0, 0);
            }
        }
        __builtin_amdgcn_s_setprio(0);
        if (t < 31) {
            f16x8 h0, h1, l0, l1;
            #pragma unroll
            for (int j = 0; j < 8; ++j) { f16 h, l; fsplit(cv[j], h, l); h0[j] = h; l0[j] = l; }
            #pragma unroll
            for (int j = 0; j < 8; ++j) { f16 h, l; fsplit(cv[8 + j], h, l); h1[j] = h; l1[j] = l; }
            char* cb = smem + 16384 + ((t + 1) & 1) * 16384 + sl * 64;
            *reinterpret_cast<f16x8*>(cb + (((ch * 32) + 0) ^ swzw))        = h0;
            *reinterpret_cast<f16x8*>(cb + (((ch * 32) + 16) ^ swzw))       = h1;
            *reinterpret_cast<f16x8*>(cb + 8192 + (((ch * 32) + 0) ^ swzw)) = l0;
            *reinterpret_cast<f16x8*>(cb + 8192 + (((ch * 32) + 16) ^ swzw))= l1;
        }
        __syncthreads();
    }

    // ---- epilogue 1: si_h (s-major) direct f16x4 stores ----
    #pragma unroll
    for (int mf = 0; mf < 2; ++mf)
        #pragma unroll
        for (int nf = 0; nf < 8; ++nf) {
            f16x4 h4;
            #pragma unroll
            for (int r = 0; r < 4; ++r) h4[r] = (f16)acc[mf][nf][r];
            const int s  = s0 + nf * 16 + l15;
            const int ib = i0 + w * 32 + mf * 16 + g * 4;
            const size_t so = ((size_t)b * Sn + s) * IDF + ib;
            *reinterpret_cast<f16x4*>(&si_h[so]) = h4;
        }

    // ---- epilogue 2: is_h (i-major) via 2-pass XOR-swizzled LDS transpose ----
    #pragma unroll
    for (int p = 0; p < 2; ++p) {
        __syncthreads();
        #pragma unroll
        for (int mf = 0; mf < 2; ++mf) {
            const int ibase = w * 32 + mf * 16 + g * 4;
            #pragma unroll
            for (int nf4 = 0; nf4 < 4; ++nf4) {
                const int sl2 = nf4 * 16 + l15;
                #pragma unroll
                for (int r = 0; r < 4; ++r) {
                    const int row = ibase + r;
                    const int byo = (sl2 * 2) ^ ((row & 7) << 4);
                    *reinterpret_cast<f16*>(smem + row * 128 + byo) = (f16)acc[mf][p * 4 + nf4][r];
                }
            }
        }
        __syncthreads();
        #pragma unroll
        for (int k = 0; k < 4; ++k) {
            const int c = tid + 256 * k;
            const int row = c >> 3, sc = (c & 7) * 8;
            const int byo = (sc * 2) ^ ((row & 7) << 4);
            const f16x8 vh = *reinterpret_cast<const f16x8*>(smem + row * 128 + byo);
            const size_t o = ((size_t)b * IDF + i0 + row) * Sn + s0 + p * 64 + sc;
            *reinterpret_cast<f16x8*>(&is_h[o]) = vh;
        }
    }
}

// ---------------------------------------------------------------------------
// K2: logits via 2-TERM split-fp16 MFMA + fused masked softmax
// NEW: depth-2 A prefetch (cvA/cvB register double buffer, even/odd-unrolled
// bodies) -- A(t+2) loads issued at iter t, consumed (split+write) at iter
// t+1 BEFORE the MFMA block. Gives every inp HBM load >=1.5 iterations of
// latency cover; MFMA order unchanged -> bit-identical outputs.
// Tile: 128q x 256s block, per-wave 128q x 64s (mf=8), wave-private B
// restage after lgkmcnt(0). LDS 48K -> 3 blocks/CU.
// LDS: A dbuf 2 x { Ah[128][64B] 8K + Al 8K } @0..32768; Bh[256][64B] @32768
// epilogue union: Pl f32 [64][132] @0, redm @34816, reds @36864
// ---------------------------------------------------------------------------
__global__ __launch_bounds__(256, 2) void k_attn(const float* __restrict__ inp,
                                                 const f16* __restrict__ si_h,
                                                 const int* __restrict__ mask,
                                                 float* __restrict__ out1,
                                                 f16* __restrict__ Ph) {
    __shared__ alignas(16) char smem[49152];
    const int tid = threadIdx.x;
    const int w = tid >> 6, lane = tid & 63, g = lane >> 4, l15 = lane & 15;
    const int rxor = ((l15 >> 1) & 3) << 4;

    // bijective XCD swizzle over 576 blocks (576 % 8 == 0)
    const int lin = blockIdx.y * 18 + blockIdx.x;
    const int swzb = (lin & 7) * 72 + (lin >> 3);
    const int b = swzb / 18, qt = swzb - b * 18;
    const int q0 = qt * 128;

    const float* Ap = inp + (size_t)b * IDF * Qn + q0;
    const f16* BhG = si_h + (size_t)b * Sn * IDF;

    // A staging: thread handles q col sl (0..127), k-chunk ch (0..1)
    const int sl = tid & 127, ch = tid >> 7;
    const int swzw = ((sl >> 1) & 3) << 4;

    f32x4 acc[8][4];
    {
        f32x4 z = {0.f, 0.f, 0.f, 0.f};
        #pragma unroll
        for (int mf = 0; mf < 8; ++mf)
            #pragma unroll
            for (int nf = 0; nf < 4; ++nf)
                acc[mf][nf] = z;
    }

    // ---- prologue: B(0) gll16; A(0) -> buf0; A(1) loads -> cvA ----
    #pragma unroll
    for (int it = 0; it < 4; ++it) {
        const int byt = w * 4096 + it * 1024 + lane * 16;
        const int s = byt >> 6;
        const int ko = ((((byt >> 4) & 3) ^ ((s >> 1) & 3)) << 3);
        const size_t go = (size_t)s * IDF + ko;
        gll16(BhG + go, smem + 32768 + w * 4096 + it * 1024);
    }
    {
        float cv[16];
        #pragma unroll
        for (int j = 0; j < 16; ++j)
            cv[j] = Ap[(size_t)(ch * 16 + j) * Qn + sl];
        f16x8 h0, h1, l0, l1;
        #pragma unroll
        for (int j = 0; j < 8; ++j) { f16 h, l; fsplit(cv[j], h, l); h0[j] = h; l0[j] = l; }
        #pragma unroll
        for (int j = 0; j < 8; ++j) { f16 h, l; fsplit(cv[8 + j], h, l); h1[j] = h; l1[j] = l; }
        char* cb = smem + sl * 64;
        *reinterpret_cast<f16x8*>(cb + (((ch * 32) + 0) ^ swzw))        = h0;
        *reinterpret_cast<f16x8*>(cb + (((ch * 32) + 16) ^ swzw))       = h1;
        *reinterpret_cast<f16x8*>(cb + 8192 + (((ch * 32) + 0) ^ swzw)) = l0;
        *reinterpret_cast<f16x8*>(cb + 8192 + (((ch * 32) + 16) ^ swzw))= l1;
    }
    float cvA[16], cvB[16];
    #pragma unroll
    for (int j = 0; j < 16; ++j)
        cvA[j] = Ap[(size_t)(32 + ch * 16 + j) * Qn + sl];
    __syncthreads();

    // body(t): cvCur holds A(t+1) (split+written this iter), cvNext gets A(t+2)
    auto body = [&](int t, float (&cvCur)[16], float (&cvNext)[16]) {
        const int kk = t * 32;
        // ---- B frag ds_reads (must complete before re-staging same slice) ----
        f16x8 fbh[4];
        #pragma unroll
        for (int nf = 0; nf < 4; ++nf) {
            const int row = w * 64 + nf * 16 + l15;
            fbh[nf] = *reinterpret_cast<const f16x8*>(smem + 32768 + row * 64 + ((g * 16) ^ rxor));
        }
        asm volatile("s_waitcnt lgkmcnt(0)" ::: "memory");
        __builtin_amdgcn_sched_barrier(0);
        if (t < 31) {
            // B(t+1) gll16 into own slice (async, lands under MFMA)
            #pragma unroll
            for (int it = 0; it < 4; ++it) {
                const int byt = w * 4096 + it * 1024 + lane * 16;
                const int s = byt >> 6;
                const int ko = ((((byt >> 4) & 3) ^ ((s >> 1) & 3)) << 3);
                const size_t go = (size_t)s * IDF + kk + 32 + ko;
                gll16(BhG + go, smem + 32768 + w * 4096 + it * 1024);
            }
        }
        if (t < 30) {
            // A(t+2) fp32 loads -> cvNext (>=1.5 iters of latency cover)
            #pragma unroll
            for (int j = 0; j < 16; ++j)
                cvNext[j] = Ap[(size_t)(kk + 64 + ch * 16 + j) * Qn + sl];
        }
        if (t < 31) {
            // split A(t+1) (loaded one iter ago) -> other buffer, BEFORE MFMA;
            // prior barrier guarantees nobody still reads buf[(t+1)&1]
            f16x8 h0, h1, l0, l1;
            #pragma unroll
            for (int j = 0; j < 8; ++j) { f16 h, l; fsplit(cvCur[j], h, l); h0[j] = h; l0[j] = l; }
            #pragma unroll
            for (int j = 0; j < 8; ++j) { f16 h, l; fsplit(cvCur[8 + j], h, l); h1[j] = h; l1[j] = l; }
            char* cb = smem + ((t + 1) & 1) * 16384 + sl * 64;
            *reinterpret_cast<f16x8*>(cb + (((ch * 32) + 0) ^ swzw))        = h0;
            *reinterpret_cast<f16x8*>(cb + (((ch * 32) + 16) ^ swzw))       = h1;
            *reinterpret_cast<f16x8*>(cb + 8192 + (((ch * 32) + 0) ^ swzw)) = l0;
            *reinterpret_cast<f16x8*>(cb + 8192 + (((ch * 32) + 16) ^ swzw))= l1;
        }
        // ---- MFMA (2-term), A frags from buf[t&1], 8 mf x 4 nf ----
        const char* ab = smem + (t & 1) * 16384;
        __builtin_amdgcn_s_setprio(1);
        #pragma unroll
        for (int mf = 0; mf < 8; ++mf) {
            const f16x8 fah = *reinterpret_cast<const f16x8*>(ab + (mf * 16 + l15) * 64 + ((g * 16) ^ rxor));
            const f16x8 fal = *reinterpret_cast<const f16x8*>(ab + 8192 + (mf * 16 + l15) * 64 + ((g * 16) ^ rxor));
            #pragma unroll
            for (int nf = 0; nf < 4; ++nf) {
                acc[mf][nf] = __builtin_amdgcn_mfma_f32_16x16x32_f16(fah, fbh[nf], acc[mf][nf], 0, 0, 0);
                acc[mf][nf] = __builtin_amdgcn_mfma_f32_16x16x32_f16(fal, fbh[nf], acc[mf][nf], 0, 0, 0);
            }
        }
        __builtin_amdgcn_s_setprio(0);
        __syncthreads();
    };

    for (int tt = 0; tt < 16; ++tt) {
        body(2 * tt,     cvA, cvB);
        body(2 * tt + 1, cvB, cvA);
    }

    // ---- masked softmax over s (q = mf*16 + g*4 + r; q%32 = (mf&1)*16+g*4+r) ----
    int mv[2][4][4];
    #pragma unroll
    for (int h2 = 0; h2 < 2; ++h2)
        #pragma unroll
        for (int r = 0; r < 4; ++r)
            #pragma unroll
            for (int nf = 0; nf < 4; ++nf)
                mv[h2][r][nf] = mask[(h2 * 16 + g * 4 + r) * Sn + w * 64 + nf * 16 + l15];

    float* redm = reinterpret_cast<float*>(smem + 34816);   // [4 waves][128 q]
    float* reds = reinterpret_cast<float*>(smem + 36864);

    float mx[8][4], sm[8][4];
    #pragma unroll
    for (int mf = 0; mf < 8; ++mf)
        #pragma unroll
        for (int r = 0; r < 4; ++r) {
            float m = -3.0e38f;
            #pragma unroll
            for (int nf = 0; nf < 4; ++nf)
                if (!mv[mf & 1][r][nf]) m = fmaxf(m, acc[mf][nf][r]);
            m = fmaxf(m, __shfl_xor(m, 1, 64));
            m = fmaxf(m, __shfl_xor(m, 2, 64));
            m = fmaxf(m, __shfl_xor(m, 4, 64));
            m = fmaxf(m, __shfl_xor(m, 8, 64));
            mx[mf][r] = m;
        }
    if (l15 == 0) {
        #pragma unroll
        for (int mf = 0; mf < 8; ++mf)
            #pragma unroll
            for (int r = 0; r < 4; ++r)
                redm[w * 128 + mf * 16 + g * 4 + r] = mx[mf][r];
    }
    __syncthreads();
    #pragma unroll
    for (int mf = 0; mf < 8; ++mf)
        #pragma unroll
        for (int r = 0; r < 4; ++r) {
            const int q = mf * 16 + g * 4 + r;
            const float gm = fmaxf(fmaxf(redm[q], redm[128 + q]), fmaxf(redm[256 + q], redm[384 + q]));
            float ssum = 0.f;
            #pragma unroll
            for (int nf = 0; nf < 4; ++nf) {
                const float p = mv[mf & 1][r][nf] ? 0.f : __expf(acc[mf][nf][r] - gm);
                acc[mf][nf][r] = p;
                ssum += p;
            }
            ssum += __shfl_xor(ssum, 1, 64);
            ssum += __shfl_xor(ssum, 2, 64);
            ssum += __shfl_xor(ssum, 4, 64);
            ssum += __shfl_xor(ssum, 8, 64);
            sm[mf][r] = ssum;
        }
    if (l15 == 0) {
        #pragma unroll
        for (int mf = 0; mf < 8; ++mf)
            #pragma unroll
            for (int r = 0; r < 4; ++r)
                reds[w * 128 + mf * 16 + g * 4 + r] = sm[mf][r];
    }
    __syncthreads();
    #pragma unroll
    for (int mf = 0; mf < 8; ++mf)
        #pragma unroll
        for (int r = 0; r < 4; ++r) {
            const int q = mf * 16 + g * 4 + r;
            const float inv = 1.0f / (reds[q] + reds[128 + q] + reds[256 + q] + reds[384 + q]);
            #pragma unroll
            for (int nf = 0; nf < 4; ++nf)
                acc[mf][nf][r] *= inv;
        }

    // ---- outputs: 4 passes of 64-s slabs; pass p owned by wave p ----
    float* Pl = reinterpret_cast<float*>(smem);              // [64 s][132 f32]
    float* O1 = out1 + (size_t)b * Sn * Qn + q0;
    f16* PhB = Ph + ((size_t)b * Qn + q0) * Sn;
    #pragma unroll
    for (int p = 0; p < 4; ++p) {
        __syncthreads();
        if (w == p) {
            #pragma unroll
            for (int mf = 0; mf < 8; ++mf)
                #pragma unroll
                for (int nf = 0; nf < 4; ++nf)
                    *reinterpret_cast<f32x4*>(
                        &Pl[(nf * 16 + l15) * 132 + mf * 16 + g * 4]) = acc[mf][nf];
        }
        __syncthreads();
        // out1: 64 s x 128 q, coalesced f32x4
        #pragma unroll
        for (int j = 0; j < 8; ++j) {
            const int sr = (tid >> 5) + j * 8;
            const int u  = (tid & 31) * 4;
            const f32x4 v = *reinterpret_cast<const f32x4*>(&Pl[sr * 132 + u]);
            *reinterpret_cast<f32x4*>(&O1[(size_t)(p * 64 + sr) * Qn + u]) = v;
        }
        // Ph: q rows 128, 32 s-pairs
        #pragma unroll
        for (int j = 0; j < 16; ++j) {
            const int colU = l15 + 16 * (j & 1);             // s-pair 0..31
            const int q    = (w * 4 + g) + 16 * (j >> 1);    // 0..127
            const float p0 = Pl[(2 * colU) * 132 + q];
            const float p1 = Pl[(2 * colU + 1) * 132 + q];
            f16x2 hh; hh[0] = (f16)p0; hh[1] = (f16)p1;
            *reinterpret_cast<f16x2*>(&PhB[(size_t)q * Sn + p * 64 + 2 * colU]) = hh;
        }
    }
}

// ---------------------------------------------------------------------------
// K3: out0[b][i][q] = sum_s srcT[b][i][s] * P[b][q][s]   (1-term, frozen;
// write-roofline-bound at ~57 us)
// ---------------------------------------------------------------------------
__global__ __launch_bounds__(256) void k_wc(const f16* __restrict__ is_h,
                                            const f16* __restrict__ Ph,
                                            float* __restrict__ out0) {
    __shared__ alignas(16) char smem[32768];
    const int tid = threadIdx.x;
    const int w = tid >> 6, lane = tid & 63, g = lane >> 4, l15 = lane & 15;
    const int wi = w >> 1, wq = w & 1;
    const int rxor = ((l15 >> 1) & 3) << 4;

    const int lin = (blockIdx.z * 8 + blockIdx.y) * 18 + blockIdx.x;
    const int swz = (lin & 7) * 576 + (lin >> 3);
    const int b = swz / 144;
    const int rr = swz - b * 144;
    const int it = rr / 18, qt = rr - it * 18;
    const int i0 = it * 128, q0 = qt * 128;

    const f16* AhG = is_h + ((size_t)b * IDF + i0) * Sn;
    const f16* BG  = Ph  + ((size_t)b * Qn + q0) * Sn;

    f32x4 acc[4][4];
    {
        f32x4 z = {0.f, 0.f, 0.f, 0.f};
        #pragma unroll
        for (int mf = 0; mf < 4; ++mf)
            #pragma unroll
            for (int nf = 0; nf < 4; ++nf)
                acc[mf][nf] = z;
    }

    #pragma unroll
    for (int t2 = 0; t2 < 2; ++t2) {
        const int byt = (w * 2 + t2) * 1024 + lane * 16;
        const int rw = byt >> 6;
        const int so = ((((byt >> 4) & 3) ^ ((rw >> 1) & 3)) << 3);
        const size_t go = (size_t)rw * Sn + so;
        gll16(AhG + go, smem + (w * 2 + t2) * 1024);
        gll16(BG  + go, smem + 8192 + (w * 2 + t2) * 1024);
    }
    __syncthreads();

    for (int t = 0; t < 8; ++t) {
        const int kk = t * 32;
        if (t < 7) {
            #pragma unroll
            for (int t2 = 0; t2 < 2; ++t2) {
                const int byt = (w * 2 + t2) * 1024 + lane * 16;
                const int rw = byt >> 6;
                const int so = ((((byt >> 4) & 3) ^ ((rw >> 1) & 3)) << 3);
                const size_t go = (size_t)rw * Sn + kk + 32 + so;
                char* dst = smem + ((t + 1) & 1) * 16384 + (w * 2 + t2) * 1024;
                gll16(AhG + go, dst);
                gll16(BG  + go, dst + 8192);
            }
        }
        const char* buf = smem + (t & 1) * 16384;
        f16x8 fah[4];
        #pragma unroll
        for (int mf = 0; mf < 4; ++mf) {
            const int row = wi * 64 + mf * 16 + l15;
            fah[mf] = *reinterpret_cast<const f16x8*>(buf + row * 64 + ((g * 16) ^ rxor));
        }
        __builtin_amdgcn_s_setprio(1);
        #pragma unroll
        for (int nf = 0; nf < 4; ++nf) {
            const int row = wq * 64 + nf * 16 + l15;
            const f16x8 fbh = *reinterpret_cast<const f16x8*>(buf + 8192 + row * 64 + ((g * 16) ^ rxor));
            #pragma unroll
            for (int mf = 0; mf < 4; ++mf)
                acc[mf][nf] = __builtin_amdgcn_mfma_f32_16x16x32_f16(fah[mf], fbh, acc[mf][nf], 0, 0, 0);
        }
        __builtin_amdgcn_s_setprio(0);
        __syncthreads();
    }
    float* O = out0 + ((size_t)b * IDF + i0 + wi * 64) * Qn + q0 + wq * 64;
    #pragma unroll
    for (int mf = 0; mf < 4; ++mf)
        #pragma unroll
        for (int nf = 0; nf < 4; ++nf)
            #pragma unroll
            for (int r = 0; r < 4; ++r)
                O[(size_t)(mf * 16 + g * 4 + r) * Qn + nf * 16 + l15] = acc[mf][nf][r];
}

extern "C" void kernel_launch(void* const* d_in, const int* in_sizes, int n_in,
                              void* d_out, int out_size, void* d_ws, size_t ws_size,
                              hipStream_t stream) {
    const float* inp  = (const float*)d_in[0];   // [B, IDF, 48, 48]
    const float* ctx  = (const float*)d_in[1];   // [B, CDF, S]
    const int*   mask = (const int*)  d_in[2];   // [B, S]
    const float* W    = (const float*)d_in[3];   // [IDF, CDF]
    float* out0 = (float*)d_out;                             // weightedContext
    float* out1 = out0 + (size_t)Bn * IDF * Qn;              // attn_out = P^T

    char* ws = (char*)d_ws;
    const size_t SZ = (size_t)Bn * Sn * IDF * sizeof(f16);   // 16 MiB
    f16* si_h = (f16*)(ws);
    f16* is_h = (f16*)(ws + 2 * SZ);
    f16* Ph   = (f16*)(ws + 4 * SZ);                         // [B][Q][S] fp16
    // W hi/lo alias the Ph region (dead until k_attn; k_srcT completes first)
    f16* Wh   = (f16*)(ws + 4 * SZ);
    f16* Wl   = Wh + (size_t)IDF * CDF;

    hipLaunchKernelGGL(k_wsplit, dim3(IDF * CDF / 1024), dim3(256), 0, stream, W, Wh, Wl);
    hipLaunchKernelGGL(k_srcT, dim3(Sn / 128, IDF / 128, Bn), dim3(256), 0, stream,
                       Wh, Wl, ctx, si_h, is_h);
    hipLaunchKernelGGL(k_attn, dim3(Qn / 128, Bn), dim3(256), 0, stream,
                       inp, si_h, mask, out1, Ph);
    hipLaunchKernelGGL(k_wc, dim3(Qn / 128, IDF / 128, Bn), dim3(256), 0, stream,
                       is_h, Ph, out0);
}